// Round 1
// baseline (18652.571 us; speedup 1.0000x reference)
//
#include <hip/hip_runtime.h>
#include <hip/hip_cooperative_groups.h>
#include <cstdint>
#include <cstddef>

namespace cg = cooperative_groups;

typedef _Float16 half8 __attribute__((ext_vector_type(8)));
typedef float f32x4 __attribute__((ext_vector_type(4)));

#define WIH3_OFF 14155776   // 3*3072*1536 (layer-3 base of W_ih)
#define WHH3_OFF 9437184    // 3*3072*1024 (layer-3 base of W_hh)

// ============================================================================
// prep: f16 conversions / transposes / bias folding / h init  (all tiny)
// ============================================================================
__global__ __launch_bounds__(256) void prep_misc_kernel(
    const float* __restrict__ embed, const float* __restrict__ W_ih,
    const float* __restrict__ dec_W1, const float* __restrict__ dec_W2,
    const float* __restrict__ b_ih, const float* __restrict__ b_hh,
    const float* __restrict__ h0,
    _Float16* __restrict__ embed16, _Float16* __restrict__ wihe16,
    _Float16* __restrict__ w1t16, _Float16* __restrict__ w2t16,
    float* __restrict__ te_bias, float* __restrict__ h32, _Float16* __restrict__ h16)
{
  int i = blockIdx.x * 256 + threadIdx.x;
  if (i < 131072) { embed16[i] = (_Float16)embed[i]; return; }
  i -= 131072;
  if (i < 1572864) {            // Wihe^T as Bt[n=row][k=e]: contiguous e-part of W_ih rows
    int r = i >> 9, e = i & 511;
    wihe16[i] = (_Float16)W_ih[WIH3_OFF + r * 1536 + 1024 + e]; return;
  }
  i -= 1572864;
  if (i < 524288) {             // W1t[d][h] = dec_W1[h][d]
    int d = i >> 10, h = i & 1023;
    w1t16[i] = (_Float16)dec_W1[h * 512 + d]; return;
  }
  i -= 524288;
  if (i < 131072) {             // W2t[v][d] = dec_W2[d][v]
    int v = i >> 9, d = i & 511;
    w2t16[i] = (_Float16)dec_W2[d * 256 + v]; return;
  }
  i -= 131072;
  if (i < 3072) {               // Te bias: b_ih (all gates) + b_hh (r,z only)
    te_bias[i] = b_ih[9216 + i] + (i < 2048 ? b_hh[9216 + i] : 0.f); return;
  }
  i -= 3072;
  if (i < 65536) {              // h state init: broadcast h0[layer 3] over batch
    float v = h0[3072 + (i & 1023)];
    h32[i] = v; h16[i] = (_Float16)v; return;
  }
}

// U[4096][1024] f16, row = j*4+g interleave so each block owns complete gate sets.
// g0: r-gate (Wih+Whh), g1: z-gate (Wih+Whh), g2: n-gate input part, g3: n-gate hidden part
__global__ __launch_bounds__(256) void prep_u_kernel(
    const float* __restrict__ W_ih, const float* __restrict__ W_hh,
    _Float16* __restrict__ U16)
{
  int i = blockIdx.x * 256 + threadIdx.x;   // < 4194304
  int row = i >> 10, k = i & 1023;
  int j = row >> 2, g = row & 3;
  const float* Wih3 = W_ih + WIH3_OFF;
  const float* Whh3 = W_hh + WHH3_OFF;
  float v;
  if (g == 0)      v = Wih3[j * 1536 + k] + Whh3[j * 1024 + k];
  else if (g == 1) v = Wih3[(1024 + j) * 1536 + k] + Whh3[(1024 + j) * 1024 + k];
  else if (g == 2) v = Wih3[(2048 + j) * 1536 + k];
  else             v = Whh3[(2048 + j) * 1024 + k];
  U16[i] = (_Float16)v;
}

// ============================================================================
// generic f16 GEMM-BT (m97 structure): C[M][N] = A[M][K] * Bt[N][K]^T + bias
// 128x128 tile, BK=32, 256 thr = 4 waves in 2x2 quadrants, global_load_lds x16
// mode 0: outF[m][n] = v          (Te)
// mode 1: outH[m][n] = relu(v)    (decoder stage 1, f16)
// mode 2: out[(b*512 + t0+(m>>6))*256 + n] = v   (logits scatter to [B][T][V])
// ============================================================================
__device__ __forceinline__ void gld_lds16(const void* g, void* l) {
  __builtin_amdgcn_global_load_lds(
      (const __attribute__((address_space(1))) unsigned int*)g,
      (__attribute__((address_space(3))) unsigned int*)l, 16, 0, 0);
}

__global__ __launch_bounds__(256) void gemm_bt_kernel(
    const _Float16* __restrict__ A, const _Float16* __restrict__ Bt,
    const float* __restrict__ bias, float* __restrict__ outF,
    _Float16* __restrict__ outH, int M, int N, int K, int mode, int t0)
{
  __shared__ _Float16 As[128 * 32];
  __shared__ _Float16 Bs[128 * 32];
  int tid = threadIdx.x, lane = tid & 63, wave = tid >> 6;
  int nbn = N >> 7;
  int bm = blockIdx.x / nbn, bn = blockIdx.x % nbn;
  int m0 = bm << 7, n0 = bn << 7;
  int wm = wave & 1, wn = wave >> 1;

  f32x4 acc[4][4];
#pragma unroll
  for (int i = 0; i < 4; i++)
#pragma unroll
    for (int j = 0; j < 4; j++) { f32x4 z = {0.f, 0.f, 0.f, 0.f}; acc[i][j] = z; }

  int aoff = ((wm << 6) + (lane & 15)) * 32 + ((lane >> 4) << 3);
  int boff = ((wn << 6) + (lane & 15)) * 32 + ((lane >> 4) << 3);

  for (int kt = 0; kt < K; kt += 32) {
    __syncthreads();                       // previous iter's LDS reads done
#pragma unroll
    for (int p = 0; p < 2; ++p) {
      int s = (p << 8) + tid;              // 0..511  -> LDS byte s*16 (lane*16 implicit)
      int row = s >> 2, seg = s & 3;
      char* ldsA = (char*)As + (p << 12) + (wave << 10);
      char* ldsB = (char*)Bs + (p << 12) + (wave << 10);
      gld_lds16(A + (size_t)(m0 + row) * K + kt + seg * 8, ldsA);
      gld_lds16(Bt + (size_t)(n0 + row) * K + kt + seg * 8, ldsB);
    }
    __syncthreads();                       // drains vmcnt -> LDS valid
    half8 af[4], bf[4];
#pragma unroll
    for (int i = 0; i < 4; ++i) af[i] = *(const half8*)&As[aoff + i * 512];
#pragma unroll
    for (int j = 0; j < 4; ++j) bf[j] = *(const half8*)&Bs[boff + j * 512];
#pragma unroll
    for (int i = 0; i < 4; ++i)
#pragma unroll
      for (int j = 0; j < 4; ++j)
        acc[i][j] = __builtin_amdgcn_mfma_f32_16x16x32_f16(af[i], bf[j], acc[i][j], 0, 0, 0);
  }

#pragma unroll
  for (int i = 0; i < 4; ++i) {
    int mbase = m0 + (wm << 6) + (i << 4) + ((lane >> 4) << 2);
#pragma unroll
    for (int j = 0; j < 4; ++j) {
      int n = n0 + (wn << 6) + (j << 4) + (lane & 15);
      float bv = bias[n];
#pragma unroll
      for (int r = 0; r < 4; ++r) {
        float v = acc[i][j][r] + bv;
        int mm = mbase + r;
        if (mode == 0)      outF[(size_t)mm * N + n] = v;
        else if (mode == 1) outH[(size_t)mm * N + n] = (_Float16)fmaxf(v, 0.f);
        else {
          int tt = t0 + (mm >> 6), b = mm & 63;
          outF[((size_t)b * 512 + tt) * 256 + n] = v;
        }
      }
    }
  }
}

// ============================================================================
// persistent GRU recurrence (cooperative, 256 blocks x 256 threads, 1/CU)
// block owns 16 U rows = 4 j-values x 4 gates; weights live in 128 VGPRs.
// Per step: 32x (16B global A-load + mfma_f32_16x16x32_f16), LDS gate exchange,
// pointwise GRU, write h16[next]/tops, grid.sync().
// ============================================================================
__global__ __launch_bounds__(256, 1) void recur_kernel(
    const _Float16* __restrict__ U16, const float* __restrict__ Te,
    const int* __restrict__ tokens, const float* __restrict__ b_hh,
    float* __restrict__ h32, _Float16* __restrict__ h16,
    _Float16* __restrict__ tops, int t0, int t1)
{
  __shared__ unsigned char ltok[32768];     // tokens[b][t] as u8 (V=256)
  __shared__ float tslice[256 * 12];        // Te slice for this block's 4 j, all 256 tokens
  __shared__ float gates[64 * 17];          // padded to kill bank conflicts
  cg::grid_group grid = cg::this_grid();
  int tid = threadIdx.x, lane = tid & 63, wave = tid >> 6;
  int blk = blockIdx.x;

  for (int i = tid; i < 32768; i += 256) ltok[i] = (unsigned char)tokens[i];
  for (int i = tid; i < 768; i += 256) {
    int v = i / 3, g = i % 3;
    const float* src = Te + (size_t)v * 3072 + g * 1024 + (blk << 2);
    *(float4*)&tslice[v * 12 + g * 4] = *(const float4*)src;
  }

  // B fragments: Bt row n = blk*16 + (lane&15), k-octet = (lane>>4)*8 + kt*32
  half8 Bf[32];
  const _Float16* Ub = U16 + (size_t)((blk << 4) + (lane & 15)) * 1024 + ((lane >> 4) << 3);
#pragma unroll
  for (int kt = 0; kt < 32; ++kt) Bf[kt] = *(const half8*)(Ub + (kt << 5));

  int cb = tid >> 2, cj = tid & 3;          // combine phase: thread owns (batch cb, j jg)
  int jg = (blk << 2) + cj;
  float bhhn = b_hh[11264 + jg];            // b_hh[3][2048 + jg]
  float hold = h32[(cb << 10) + jg];        // fp32 master state in a register
  __syncthreads();

  const _Float16* hbase = h16 + ((size_t)(wave << 4) + (lane & 15)) * 1024 + ((lane >> 4) << 3);

  for (int t = t0; t < t1; ++t) {
    const _Float16* hb = hbase + (size_t)(t & 1) * 65536;
    f32x4 acc = {0.f, 0.f, 0.f, 0.f};
#pragma unroll
    for (int kt = 0; kt < 32; ++kt) {
      half8 a = *(const half8*)(hb + (kt << 5));
      acc = __builtin_amdgcn_mfma_f32_16x16x32_f16(a, Bf[kt], acc, 0, 0, 0);
    }
    // C layout: col = lane&15 (local U row), row = (lane>>4)*4 + r (local batch)
#pragma unroll
    for (int r = 0; r < 4; ++r)
      gates[((wave << 4) + ((lane >> 4) << 2) + r) * 17 + (lane & 15)] = acc[r];
    __syncthreads();

    float g0 = gates[cb * 17 + (cj << 2) + 0];   // r pre-act (h part)
    float g1 = gates[cb * 17 + (cj << 2) + 1];   // z pre-act (h part)
    float g2 = gates[cb * 17 + (cj << 2) + 2];   // n input part
    float g3 = gates[cb * 17 + (cj << 2) + 3];   // n hidden part
    int tok = ltok[(cb << 9) + t];
    float te0 = tslice[tok * 12 + cj];
    float te1 = tslice[tok * 12 + 4 + cj];
    float te2 = tslice[tok * 12 + 8 + cj];
    float rr = 1.f / (1.f + __expf(-(g0 + te0)));
    float zz = 1.f / (1.f + __expf(-(g1 + te1)));
    float nv = tanhf(g2 + te2 + rr * (g3 + bhhn));
    float hnew = (1.f - zz) * nv + zz * hold;
    hold = hnew;
    _Float16 hh = (_Float16)hnew;
    h16[(size_t)((t + 1) & 1) * 65536 + (cb << 10) + jg] = hh;
    tops[(size_t)(t - t0) * 65536 + (cb << 10) + jg] = hh;
    grid.sync();
  }
  h32[(cb << 10) + jg] = hold;              // carry state across chunk launches
}

// ============================================================================
extern "C" void kernel_launch(void* const* d_in, const int* in_sizes, int n_in,
                              void* d_out, int out_size, void* d_ws, size_t ws_size,
                              hipStream_t stream) {
  const int*   tokens = (const int*)d_in[0];
  const float* embed  = (const float*)d_in[1];
  const float* W_ih   = (const float*)d_in[2];
  const float* W_hh   = (const float*)d_in[3];
  const float* b_ih   = (const float*)d_in[4];
  const float* b_hh   = (const float*)d_in[5];
  const float* h0     = (const float*)d_in[6];
  const float* dec_W1 = (const float*)d_in[7];
  const float* dec_b1 = (const float*)d_in[8];
  const float* dec_W2 = (const float*)d_in[9];
  const float* dec_b2 = (const float*)d_in[10];
  float* out = (float*)d_out;
  (void)in_sizes; (void)n_in; (void)out_size;

  char* ws = (char*)d_ws;
  size_t off = 0;
  auto alloc = [&](size_t bytes) -> char* {
    char* p = ws + off;
    off = (off + bytes + 255) & ~(size_t)255;
    return p;
  };
  _Float16* U16     = (_Float16*)alloc((size_t)4096 * 1024 * 2);
  float*    Te      = (float*)alloc((size_t)256 * 3072 * 4);
  float*    te_bias = (float*)alloc(3072 * 4);
  _Float16* embed16 = (_Float16*)alloc(131072 * 2);
  _Float16* wihe16  = (_Float16*)alloc((size_t)1572864 * 2);
  _Float16* w1t16   = (_Float16*)alloc(524288 * 2);
  _Float16* w2t16   = (_Float16*)alloc(131072 * 2);
  float*    h32     = (float*)alloc(65536 * 4);
  _Float16* h16     = (_Float16*)alloc((size_t)2 * 65536 * 2);
  size_t fixed = off;

  // chunk T so tops (T*64*1024 f16) + hdec (T*64*512 f16) fit in the workspace
  size_t per_t = (size_t)(65536 + 32768) * 2;    // 196608 B per timestep
  long remain = (long)ws_size - (long)fixed - 1024;
  int chunk_T = remain > 0 ? (int)(remain / (long)per_t) : 0;
  chunk_T &= ~1;
  if (chunk_T > 512) chunk_T = 512;
  if (chunk_T < 2) chunk_T = 2;
  _Float16* tops = (_Float16*)alloc((size_t)chunk_T * 65536 * 2);
  _Float16* hdec = (_Float16*)alloc((size_t)chunk_T * 32768 * 2);

  prep_misc_kernel<<<9484, 256, 0, stream>>>(embed, W_ih, dec_W1, dec_W2, b_ih, b_hh, h0,
                                             embed16, wihe16, w1t16, w2t16, te_bias, h32, h16);
  prep_u_kernel<<<16384, 256, 0, stream>>>(W_ih, W_hh, U16);
  // Te[v][3072] = embed_f16[v] . Wihe^T + folded biases
  gemm_bt_kernel<<<2 * 24, 256, 0, stream>>>(embed16, wihe16, te_bias, Te, nullptr,
                                             256, 3072, 512, 0, 0);

  for (int t0 = 0; t0 < 512; t0 += chunk_T) {
    int t1 = t0 + chunk_T; if (t1 > 512) t1 = 512;
    void* args[] = {&U16, &Te, (void*)&tokens, (void*)&b_hh, &h32, &h16, &tops, &t0, &t1};
    hipLaunchCooperativeKernel((const void*)recur_kernel, dim3(256), dim3(256), args, 0, stream);
    int Mc = (t1 - t0) * 64;
    gemm_bt_kernel<<<(Mc / 128) * 4, 256, 0, stream>>>(tops, w1t16, dec_b1, nullptr, hdec,
                                                       Mc, 512, 1024, 1, 0);
    gemm_bt_kernel<<<(Mc / 128) * 2, 256, 0, stream>>>(hdec, w2t16, dec_b2, out, nullptr,
                                                       Mc, 256, 512, 2, t0);
  }
}

// Round 3
// 2708.533 us; speedup vs baseline: 6.8866x; 6.8866x over previous
//
#include <hip/hip_runtime.h>
#include <cstdint>
#include <cstddef>

typedef _Float16 half8 __attribute__((ext_vector_type(8)));
typedef float f32x4 __attribute__((ext_vector_type(4)));

#define WIH3_OFF 14155776   // 3*3072*1536 (layer-3 base of W_ih)
#define WHH3_OFF 9437184    // 3*3072*1024 (layer-3 base of W_hh)

// ============================================================================
// prep: f16 conversions / transposes / bias folding / h init / barrier zero
// ============================================================================
__global__ __launch_bounds__(256) void prep_misc_kernel(
    const float* __restrict__ embed, const float* __restrict__ W_ih,
    const float* __restrict__ dec_W1, const float* __restrict__ dec_W2,
    const float* __restrict__ b_ih, const float* __restrict__ b_hh,
    const float* __restrict__ h0,
    _Float16* __restrict__ embed16, _Float16* __restrict__ wihe16,
    _Float16* __restrict__ w1t16, _Float16* __restrict__ w2t16,
    float* __restrict__ te_bias, float* __restrict__ h32, _Float16* __restrict__ h16,
    unsigned int* __restrict__ bar)
{
  int i = blockIdx.x * 256 + threadIdx.x;
  if (i < 131072) { embed16[i] = (_Float16)embed[i]; return; }
  i -= 131072;
  if (i < 1572864) {            // Wihe^T as Bt[n=row][k=e]: contiguous e-part of W_ih rows
    int r = i >> 9, e = i & 511;
    wihe16[i] = (_Float16)W_ih[WIH3_OFF + r * 1536 + 1024 + e]; return;
  }
  i -= 1572864;
  if (i < 524288) {             // W1t[d][h] = dec_W1[h][d]
    int d = i >> 10, h = i & 1023;
    w1t16[i] = (_Float16)dec_W1[h * 512 + d]; return;
  }
  i -= 524288;
  if (i < 131072) {             // W2t[v][d] = dec_W2[d][v]
    int v = i >> 9, d = i & 511;
    w2t16[i] = (_Float16)dec_W2[d * 256 + v]; return;
  }
  i -= 131072;
  if (i < 3072) {               // Te bias: b_ih (all gates) + b_hh (r,z only)
    te_bias[i] = b_ih[9216 + i] + (i < 2048 ? b_hh[9216 + i] : 0.f); return;
  }
  i -= 3072;
  if (i < 65536) {              // h state init: broadcast h0[layer 3] over batch
    float v = h0[3072 + (i & 1023)];
    h32[i] = v; h16[i] = (_Float16)v; return;
  }
  i -= 65536;
  if (i < 65536) { bar[i] = 0u; return; }   // barrier slots: 512 steps x 8 lines x 16 u32
}

// U[4096][1024] f16, row = j*4+g interleave so each block owns complete gate sets.
// g0: r-gate (Wih+Whh), g1: z-gate (Wih+Whh), g2: n-gate input part, g3: n-gate hidden part
__global__ __launch_bounds__(256) void prep_u_kernel(
    const float* __restrict__ W_ih, const float* __restrict__ W_hh,
    _Float16* __restrict__ U16)
{
  int i = blockIdx.x * 256 + threadIdx.x;   // < 4194304
  int row = i >> 10, k = i & 1023;
  int j = row >> 2, g = row & 3;
  const float* Wih3 = W_ih + WIH3_OFF;
  const float* Whh3 = W_hh + WHH3_OFF;
  float v;
  if (g == 0)      v = Wih3[j * 1536 + k] + Whh3[j * 1024 + k];
  else if (g == 1) v = Wih3[(1024 + j) * 1536 + k] + Whh3[(1024 + j) * 1024 + k];
  else if (g == 2) v = Wih3[(2048 + j) * 1536 + k];
  else             v = Whh3[(2048 + j) * 1024 + k];
  U16[i] = (_Float16)v;
}

// ============================================================================
// generic f16 GEMM-BT (m97 structure): C[M][N] = A[M][K] * Bt[N][K]^T + bias
// mode 0: outF[m][n]=v (Te)   mode 1: outH=relu(v) f16   mode 2: logits scatter
// ============================================================================
__device__ __forceinline__ void gld_lds16(const void* g, void* l) {
  __builtin_amdgcn_global_load_lds(
      (const __attribute__((address_space(1))) unsigned int*)g,
      (__attribute__((address_space(3))) unsigned int*)l, 16, 0, 0);
}

__global__ __launch_bounds__(256) void gemm_bt_kernel(
    const _Float16* __restrict__ A, const _Float16* __restrict__ Bt,
    const float* __restrict__ bias, float* __restrict__ outF,
    _Float16* __restrict__ outH, int M, int N, int K, int mode, int t0)
{
  __shared__ _Float16 As[128 * 32];
  __shared__ _Float16 Bs[128 * 32];
  int tid = threadIdx.x, lane = tid & 63, wave = tid >> 6;
  int nbn = N >> 7;
  int bm = blockIdx.x / nbn, bn = blockIdx.x % nbn;
  int m0 = bm << 7, n0 = bn << 7;
  int wm = wave & 1, wn = wave >> 1;

  f32x4 acc[4][4];
#pragma unroll
  for (int i = 0; i < 4; i++)
#pragma unroll
    for (int j = 0; j < 4; j++) { f32x4 z = {0.f, 0.f, 0.f, 0.f}; acc[i][j] = z; }

  int aoff = ((wm << 6) + (lane & 15)) * 32 + ((lane >> 4) << 3);
  int boff = ((wn << 6) + (lane & 15)) * 32 + ((lane >> 4) << 3);

  for (int kt = 0; kt < K; kt += 32) {
    __syncthreads();
#pragma unroll
    for (int p = 0; p < 2; ++p) {
      int s = (p << 8) + tid;
      int row = s >> 2, seg = s & 3;
      char* ldsA = (char*)As + (p << 12) + (wave << 10);
      char* ldsB = (char*)Bs + (p << 12) + (wave << 10);
      gld_lds16(A + (size_t)(m0 + row) * K + kt + seg * 8, ldsA);
      gld_lds16(Bt + (size_t)(n0 + row) * K + kt + seg * 8, ldsB);
    }
    __syncthreads();
    half8 af[4], bf[4];
#pragma unroll
    for (int i = 0; i < 4; ++i) af[i] = *(const half8*)&As[aoff + i * 512];
#pragma unroll
    for (int j = 0; j < 4; ++j) bf[j] = *(const half8*)&Bs[boff + j * 512];
#pragma unroll
    for (int i = 0; i < 4; ++i)
#pragma unroll
      for (int j = 0; j < 4; ++j)
        acc[i][j] = __builtin_amdgcn_mfma_f32_16x16x32_f16(af[i], bf[j], acc[i][j], 0, 0, 0);
  }

#pragma unroll
  for (int i = 0; i < 4; ++i) {
    int mbase = m0 + (wm << 6) + (i << 4) + ((lane >> 4) << 2);
#pragma unroll
    for (int j = 0; j < 4; ++j) {
      int n = n0 + (wn << 6) + (j << 4) + (lane & 15);
      float bv = bias[n];
#pragma unroll
      for (int r = 0; r < 4; ++r) {
        float v = acc[i][j][r] + bv;
        int mm = mbase + r;
        if (mode == 0)      outF[(size_t)mm * N + n] = v;
        else if (mode == 1) outH[(size_t)mm * N + n] = (_Float16)fmaxf(v, 0.f);
        else {
          int tt = t0 + (mm >> 6), b = mm & 63;
          outF[((size_t)b * 512 + tt) * 256 + n] = v;
        }
      }
    }
  }
}

// ============================================================================
// persistent GRU recurrence: 256 blocks = 64 rowgroups x 4 batchgroups.
// Block (rg,bg): U rows [rg*64, rg*64+64) (wave w holds 16 rows in 128 VGPRs),
// batches [bg*16, bg*16+16). Per step: stage 32KB h-slice -> LDS (sc0sc1
// coherent loads), 32 MFMA/wave, LDS gate exchange, pointwise GRU, sc0sc1
// write-through h stores, inline split-counter grid barrier (no L2 inv, no call).
// ============================================================================
__global__ __launch_bounds__(256, 1) void recur_kernel(
    const _Float16* __restrict__ U16, const float* __restrict__ Te,
    const int* __restrict__ tokens, const float* __restrict__ b_hh,
    float* __restrict__ h32, _Float16* __restrict__ h16,
    _Float16* __restrict__ tops, unsigned int* __restrict__ bar, int t0, int t1)
{
  __shared__ _Float16 hs[16 * 1032];        // h slice, row stride 1032 (pad 16B)
  __shared__ float gates[16 * 68];          // [batch][64 rows + pad]
  __shared__ unsigned char ltok[16 * 512];  // this block's tokens
  __shared__ _Float16 hrep[16 * 24];        // h_new repack for 16B stores

  int tid = threadIdx.x, lane = tid & 63, w = tid >> 6;
  int rg = blockIdx.x >> 2, bg = blockIdx.x & 3;

  for (int i = tid; i < 8192; i += 256)
    ltok[i] = (unsigned char)tokens[((bg << 4) + (i >> 9)) * 512 + (i & 511)];

  // weights: wave w -> local rows w*16+(lane&15), all 32 k-octets (128 VGPRs)
  half8 Bf[32];
  {
    const _Float16* Ub = U16 + (size_t)((rg << 6) + (w << 4) + (lane & 15)) * 1024 + ((lane >> 4) << 3);
#pragma unroll
    for (int kt = 0; kt < 32; ++kt) Bf[kt] = *(const half8*)(Ub + (kt << 5));
  }

  int lb = tid >> 4, jl = tid & 15;         // combine ownership: (batch lb, j jl)
  int j = (rg << 4) + jl;
  int b = (bg << 4) + lb;
  float bhhn = b_hh[11264 + j];
  float hold = h32[(b << 10) + j];
  const float* tebase = Te + j;             // + tok*3072 + g*1024
  __syncthreads();

  const _Float16* hsA = &hs[(lane & 15) * 1032 + ((lane >> 4) << 3)];
  int srow = tid >> 6, scol = tid & 63;     // staging: 4 rowgroups x 2 col-halves

  for (int t = t0; t < t1; ++t) {
    // ---- stage h slice (16 x 1024 f16 = 32KB) into LDS, coherent loads ----
    // tiles: rows {0,4,8,12}+srow  x  cols {0,512}+scol*8
    {
      const _Float16* gsrc = h16 + (size_t)(t & 1) * 65536 + ((size_t)bg << 14)
                             + ((size_t)srow << 10) + (scol << 3);
      f32x4 r0, r1, r2, r3, r4, r5, r6, r7;
      asm volatile(
        "global_load_dwordx4 %0, %8, off sc0 sc1\n\t"
        "global_load_dwordx4 %1, %9, off sc0 sc1\n\t"
        "global_load_dwordx4 %2, %10, off sc0 sc1\n\t"
        "global_load_dwordx4 %3, %11, off sc0 sc1\n\t"
        "global_load_dwordx4 %4, %12, off sc0 sc1\n\t"
        "global_load_dwordx4 %5, %13, off sc0 sc1\n\t"
        "global_load_dwordx4 %6, %14, off sc0 sc1\n\t"
        "global_load_dwordx4 %7, %15, off sc0 sc1\n\t"
        "s_waitcnt vmcnt(0)"
        : "=&v"(r0), "=&v"(r1), "=&v"(r2), "=&v"(r3),
          "=&v"(r4), "=&v"(r5), "=&v"(r6), "=&v"(r7)
        : "v"(gsrc), "v"(gsrc + 512), "v"(gsrc + 4096), "v"(gsrc + 4608),
          "v"(gsrc + 8192), "v"(gsrc + 8704), "v"(gsrc + 12288), "v"(gsrc + 12800)
        : "memory");
      _Float16* ldst = &hs[srow * 1032 + (scol << 3)];
      *(f32x4*)(ldst)          = r0;  *(f32x4*)(ldst + 512)   = r1;
      *(f32x4*)(ldst + 4128)   = r2;  *(f32x4*)(ldst + 4640)  = r3;
      *(f32x4*)(ldst + 8256)   = r4;  *(f32x4*)(ldst + 8768)  = r5;
      *(f32x4*)(ldst + 12384)  = r6;  *(f32x4*)(ldst + 12896) = r7;
    }
    __syncthreads();

    // ---- matvec: one 16x16 tile per wave, 2 independent acc chains ----
    f32x4 a0 = {0.f, 0.f, 0.f, 0.f}, a1 = {0.f, 0.f, 0.f, 0.f};
#pragma unroll
    for (int kt = 0; kt < 32; kt += 2) {
      half8 x0 = *(const half8*)(hsA + (kt << 5));
      half8 x1 = *(const half8*)(hsA + (kt << 5) + 32);
      a0 = __builtin_amdgcn_mfma_f32_16x16x32_f16(x0, Bf[kt], a0, 0, 0, 0);
      a1 = __builtin_amdgcn_mfma_f32_16x16x32_f16(x1, Bf[kt + 1], a1, 0, 0, 0);
    }
    f32x4 acc = a0 + a1;
    int lr = (w << 4) + (lane & 15);        // local row 0..63 = jl*4+g
#pragma unroll
    for (int r = 0; r < 4; ++r)
      gates[(((lane >> 4) << 2) + r) * 68 + lr] = acc[r];
    __syncthreads();

    // ---- pointwise GRU (thread owns (lb, jl)) ----
    float4 g = *(const float4*)&gates[lb * 68 + (jl << 2)];
    int tok = ltok[(lb << 9) + t];
    const float* te = tebase + tok * 3072;
    float te0 = te[0], te1 = te[1024], te2 = te[2048];
    float rr = 1.f / (1.f + __expf(-(g.x + te0)));
    float zz = 1.f / (1.f + __expf(-(g.y + te1)));
    float nv = tanhf(g.z + te2 + rr * (g.w + bhhn));
    float hnew = (1.f - zz) * nv + zz * hold;
    hold = hnew;
    hrep[lb * 24 + jl] = (_Float16)hnew;
    __syncthreads();

    // ---- writeback: 32 threads store 16B each (h16 coherent, tops cached) ----
    if (tid < 32) {
      int wb = tid >> 1, c = tid & 1;
      f32x4 v = *(const f32x4*)&hrep[wb * 24 + (c << 3)];
      _Float16* dst = h16 + (size_t)((t + 1) & 1) * 65536
                      + ((size_t)(((bg << 4) + wb)) << 10) + (rg << 4) + (c << 3);
      asm volatile("global_store_dwordx4 %0, %1, off sc0 sc1" :: "v"(dst), "v"(v) : "memory");
      *(f32x4*)(tops + ((size_t)(t - t0) << 16)
                + ((size_t)(((bg << 4) + wb)) << 10) + (rg << 4) + (c << 3)) = v;
    }
    asm volatile("s_waitcnt vmcnt(0)" ::: "memory");
    __syncthreads();

    // ---- inline grid barrier: 8 split counters, 64B apart, slot = step t ----
    if (tid < 8) {
      unsigned int* line = bar + (t << 7) + (tid << 4);
      if (tid == (int)(blockIdx.x & 7))
        __hip_atomic_fetch_add(line, 1u, __ATOMIC_RELAXED, __HIP_MEMORY_SCOPE_AGENT);
      while (__hip_atomic_load(line, __ATOMIC_RELAXED, __HIP_MEMORY_SCOPE_AGENT) != 32u) {}
    }
    __syncthreads();
  }
  h32[(b << 10) + j] = hold;
}

// ============================================================================
extern "C" void kernel_launch(void* const* d_in, const int* in_sizes, int n_in,
                              void* d_out, int out_size, void* d_ws, size_t ws_size,
                              hipStream_t stream) {
  const int*   tokens = (const int*)d_in[0];
  const float* embed  = (const float*)d_in[1];
  const float* W_ih   = (const float*)d_in[2];
  const float* W_hh   = (const float*)d_in[3];
  const float* b_ih   = (const float*)d_in[4];
  const float* b_hh   = (const float*)d_in[5];
  const float* h0     = (const float*)d_in[6];
  const float* dec_W1 = (const float*)d_in[7];
  const float* dec_b1 = (const float*)d_in[8];
  const float* dec_W2 = (const float*)d_in[9];
  const float* dec_b2 = (const float*)d_in[10];
  float* out = (float*)d_out;
  (void)in_sizes; (void)n_in; (void)out_size;

  char* ws = (char*)d_ws;
  size_t off = 0;
  auto alloc = [&](size_t bytes) -> char* {
    char* p = ws + off;
    off = (off + bytes + 255) & ~(size_t)255;
    return p;
  };
  _Float16* U16     = (_Float16*)alloc((size_t)4096 * 1024 * 2);
  float*    Te      = (float*)alloc((size_t)256 * 3072 * 4);
  float*    te_bias = (float*)alloc(3072 * 4);
  _Float16* embed16 = (_Float16*)alloc(131072 * 2);
  _Float16* wihe16  = (_Float16*)alloc((size_t)1572864 * 2);
  _Float16* w1t16   = (_Float16*)alloc(524288 * 2);
  _Float16* w2t16   = (_Float16*)alloc(131072 * 2);
  float*    h32     = (float*)alloc(65536 * 4);
  _Float16* h16     = (_Float16*)alloc((size_t)2 * 65536 * 2);
  unsigned int* bar = (unsigned int*)alloc((size_t)65536 * 4);
  size_t fixed = off;

  size_t per_t = (size_t)(65536 + 32768) * 2;
  long remain = (long)ws_size - (long)fixed - 1024;
  int chunk_T = remain > 0 ? (int)(remain / (long)per_t) : 0;
  chunk_T &= ~1;
  if (chunk_T > 512) chunk_T = 512;
  if (chunk_T < 2) chunk_T = 2;
  _Float16* tops = (_Float16*)alloc((size_t)chunk_T * 65536 * 2);
  _Float16* hdec = (_Float16*)alloc((size_t)chunk_T * 32768 * 2);

  prep_misc_kernel<<<9740, 256, 0, stream>>>(embed, W_ih, dec_W1, dec_W2, b_ih, b_hh, h0,
                                             embed16, wihe16, w1t16, w2t16, te_bias, h32, h16, bar);
  prep_u_kernel<<<16384, 256, 0, stream>>>(W_ih, W_hh, U16);
  gemm_bt_kernel<<<2 * 24, 256, 0, stream>>>(embed16, wihe16, te_bias, Te, nullptr,
                                             256, 3072, 512, 0, 0);

  for (int t0 = 0; t0 < 512; t0 += chunk_T) {
    int t1 = t0 + chunk_T; if (t1 > 512) t1 = 512;
    void* args[] = {&U16, &Te, (void*)&tokens, (void*)&b_hh, &h32, &h16, &tops, &bar, &t0, &t1};
    hipLaunchCooperativeKernel((const void*)recur_kernel, dim3(256), dim3(256), args, 0, stream);
    int Mc = (t1 - t0) * 64;
    gemm_bt_kernel<<<(Mc / 128) * 4, 256, 0, stream>>>(tops, w1t16, dec_b1, nullptr, hdec,
                                                       Mc, 512, 1024, 1, 0);
    gemm_bt_kernel<<<(Mc / 128) * 2, 256, 0, stream>>>(hdec, w2t16, dec_b2, out, nullptr,
                                                       Mc, 256, 512, 2, t0);
  }
}

// Round 4
// 2291.857 us; speedup vs baseline: 8.1386x; 1.1818x over previous
//
#include <hip/hip_runtime.h>
#include <cstdint>
#include <cstddef>

typedef _Float16 half8 __attribute__((ext_vector_type(8)));
typedef float f32x4 __attribute__((ext_vector_type(4)));

#define WIH3_OFF 14155776   // 3*3072*1536 (layer-3 base of W_ih)
#define WHH3_OFF 9437184    // 3*3072*1024 (layer-3 base of W_hh)

// ============================================================================
// prep: f16 conversions / transposes / bias folding / h init / barrier zero
// ============================================================================
__global__ __launch_bounds__(256) void prep_misc_kernel(
    const float* __restrict__ embed, const float* __restrict__ W_ih,
    const float* __restrict__ dec_W1, const float* __restrict__ dec_W2,
    const float* __restrict__ b_ih, const float* __restrict__ b_hh,
    const float* __restrict__ h0,
    _Float16* __restrict__ embed16, _Float16* __restrict__ wihe16,
    _Float16* __restrict__ w1t16, _Float16* __restrict__ w2t16,
    float* __restrict__ te_bias, float* __restrict__ h32, _Float16* __restrict__ h16,
    unsigned int* __restrict__ bar)
{
  int i = blockIdx.x * 256 + threadIdx.x;
  if (i < 131072) { embed16[i] = (_Float16)embed[i]; return; }
  i -= 131072;
  if (i < 1572864) {            // Wihe^T as Bt[n=row][k=e]: contiguous e-part of W_ih rows
    int r = i >> 9, e = i & 511;
    wihe16[i] = (_Float16)W_ih[WIH3_OFF + r * 1536 + 1024 + e]; return;
  }
  i -= 1572864;
  if (i < 524288) {             // W1t[d][h] = dec_W1[h][d]
    int d = i >> 10, h = i & 1023;
    w1t16[i] = (_Float16)dec_W1[h * 512 + d]; return;
  }
  i -= 524288;
  if (i < 131072) {             // W2t[v][d] = dec_W2[d][v]
    int v = i >> 9, d = i & 511;
    w2t16[i] = (_Float16)dec_W2[d * 256 + v]; return;
  }
  i -= 131072;
  if (i < 3072) {               // Te bias: b_ih (all gates) + b_hh (r,z only)
    te_bias[i] = b_ih[9216 + i] + (i < 2048 ? b_hh[9216 + i] : 0.f); return;
  }
  i -= 3072;
  if (i < 65536) {              // h state init: broadcast h0[layer 3] over batch
    float v = h0[3072 + (i & 1023)];
    h32[i] = v; h16[i] = (_Float16)v; return;
  }
  i -= 65536;
  if (i < 65536) { bar[i] = 0u; return; }   // barrier slots: 512 steps x 8 lines x 16 u32
}

// U[4096][1024] f16, row = j*4+g interleave so each block owns complete gate sets.
// g0: r-gate (Wih+Whh), g1: z-gate (Wih+Whh), g2: n-gate input part, g3: n-gate hidden part
__global__ __launch_bounds__(256) void prep_u_kernel(
    const float* __restrict__ W_ih, const float* __restrict__ W_hh,
    _Float16* __restrict__ U16)
{
  int i = blockIdx.x * 256 + threadIdx.x;   // < 4194304
  int row = i >> 10, k = i & 1023;
  int j = row >> 2, g = row & 3;
  const float* Wih3 = W_ih + WIH3_OFF;
  const float* Whh3 = W_hh + WHH3_OFF;
  float v;
  if (g == 0)      v = Wih3[j * 1536 + k] + Whh3[j * 1024 + k];
  else if (g == 1) v = Wih3[(1024 + j) * 1536 + k] + Whh3[(1024 + j) * 1024 + k];
  else if (g == 2) v = Wih3[(2048 + j) * 1536 + k];
  else             v = Whh3[(2048 + j) * 1024 + k];
  U16[i] = (_Float16)v;
}

// ============================================================================
// generic f16 GEMM-BT (m97 structure): C[M][N] = A[M][K] * Bt[N][K]^T + bias
// mode 0: outF[m][n]=v (Te)   mode 1: outH=relu(v) f16   mode 2: logits scatter
// ============================================================================
__device__ __forceinline__ void gld_lds16(const void* g, void* l) {
  __builtin_amdgcn_global_load_lds(
      (const __attribute__((address_space(1))) unsigned int*)g,
      (__attribute__((address_space(3))) unsigned int*)l, 16, 0, 0);
}

__global__ __launch_bounds__(256) void gemm_bt_kernel(
    const _Float16* __restrict__ A, const _Float16* __restrict__ Bt,
    const float* __restrict__ bias, float* __restrict__ outF,
    _Float16* __restrict__ outH, int M, int N, int K, int mode, int t0)
{
  __shared__ _Float16 As[128 * 32];
  __shared__ _Float16 Bs[128 * 32];
  int tid = threadIdx.x, lane = tid & 63, wave = tid >> 6;
  int nbn = N >> 7;
  int bm = blockIdx.x / nbn, bn = blockIdx.x % nbn;
  int m0 = bm << 7, n0 = bn << 7;
  int wm = wave & 1, wn = wave >> 1;

  f32x4 acc[4][4];
#pragma unroll
  for (int i = 0; i < 4; i++)
#pragma unroll
    for (int j = 0; j < 4; j++) { f32x4 z = {0.f, 0.f, 0.f, 0.f}; acc[i][j] = z; }

  int aoff = ((wm << 6) + (lane & 15)) * 32 + ((lane >> 4) << 3);
  int boff = ((wn << 6) + (lane & 15)) * 32 + ((lane >> 4) << 3);

  for (int kt = 0; kt < K; kt += 32) {
    __syncthreads();
#pragma unroll
    for (int p = 0; p < 2; ++p) {
      int s = (p << 8) + tid;
      int row = s >> 2, seg = s & 3;
      char* ldsA = (char*)As + (p << 12) + (wave << 10);
      char* ldsB = (char*)Bs + (p << 12) + (wave << 10);
      gld_lds16(A + (size_t)(m0 + row) * K + kt + seg * 8, ldsA);
      gld_lds16(Bt + (size_t)(n0 + row) * K + kt + seg * 8, ldsB);
    }
    __syncthreads();
    half8 af[4], bf[4];
#pragma unroll
    for (int i = 0; i < 4; ++i) af[i] = *(const half8*)&As[aoff + i * 512];
#pragma unroll
    for (int j = 0; j < 4; ++j) bf[j] = *(const half8*)&Bs[boff + j * 512];
#pragma unroll
    for (int i = 0; i < 4; ++i)
#pragma unroll
      for (int j = 0; j < 4; ++j)
        acc[i][j] = __builtin_amdgcn_mfma_f32_16x16x32_f16(af[i], bf[j], acc[i][j], 0, 0, 0);
  }

#pragma unroll
  for (int i = 0; i < 4; ++i) {
    int mbase = m0 + (wm << 6) + (i << 4) + ((lane >> 4) << 2);
#pragma unroll
    for (int j = 0; j < 4; ++j) {
      int n = n0 + (wn << 6) + (j << 4) + (lane & 15);
      float bv = bias[n];
#pragma unroll
      for (int r = 0; r < 4; ++r) {
        float v = acc[i][j][r] + bv;
        int mm = mbase + r;
        if (mode == 0)      outF[(size_t)mm * N + n] = v;
        else if (mode == 1) outH[(size_t)mm * N + n] = (_Float16)fmaxf(v, 0.f);
        else {
          int tt = t0 + (mm >> 6), b = mm & 63;
          outF[((size_t)b * 512 + tt) * 256 + n] = v;
        }
      }
    }
  }
}

// ============================================================================
// persistent GRU recurrence v3: 256 blocks = 64 rowgroups x 4 batchgroups.
// K-SPLIT across waves: wave w owns k in [w*256, w*256+256) for ALL 64 local
// rows (Bf[4][8] = 128 regs -> AGPRs). h staged in MFMA-fragment order with
// XOR-batch swizzle: staging writes AND fragment reads are bank-conflict-free;
// LDS read traffic 32KB/step (was 128KB). f32 partial sums exchanged via LDS.
// ============================================================================
__global__ __launch_bounds__(256, 1) void recur_kernel(
    const _Float16* __restrict__ U16, const float* __restrict__ Te,
    const int* __restrict__ tokens, const float* __restrict__ b_hh,
    float* __restrict__ h32, _Float16* __restrict__ h16,
    _Float16* __restrict__ tops, unsigned int* __restrict__ bar, int t0, int t1)
{
  __shared__ _Float16 hs[16384];           // fragment order: [c 0..127][b^(c&15)][8]
  __shared__ float part[4 * 64 * 20];      // [wave][urow 0..63][batch 0..15 +4 pad]
  __shared__ unsigned char ltok[8192];     // this block's tokens
  __shared__ _Float16 hrep[16 * 24];       // h_new repack for 16B stores

  int tid = threadIdx.x, lane = tid & 63, w = tid >> 6;
  int rg = blockIdx.x >> 2, bg = blockIdx.x & 3;

  for (int i = tid; i < 8192; i += 256)
    ltok[i] = (unsigned char)tokens[((bg << 4) + (i >> 9)) * 512 + (i & 511)];

  // B fragments: wave w -> all 4 row-tiles, k-octets w*32 + kt*4 + quad
  half8 Bf[4][8];
  {
    const _Float16* Ub = U16 + (size_t)((rg << 6) + (lane & 15)) * 1024
                         + (w << 8) + ((lane >> 4) << 3);
#pragma unroll
    for (int rt = 0; rt < 4; ++rt)
#pragma unroll
      for (int kt = 0; kt < 8; ++kt)
        Bf[rt][kt] = *(const half8*)(Ub + rt * 16384 + (kt << 5));
  }

  int lb = tid >> 4, jl = tid & 15;         // combine ownership: (batch lb, j jl)
  int j = (rg << 4) + jl;
  int b = (bg << 4) + lb;
  float bhhn = b_hh[11264 + j];
  float hold = h32[(b << 10) + j];
  const float* tebase = Te + j;             // + tok*3072 + g*1024

  int srow0 = tid >> 7;                     // staging: batch parity
  int ccol  = tid & 127;                    // staging: k-octet c
  int cx    = ccol & 15;
  int c0    = (w << 5) + (lane >> 4);       // fragment read: base k-octet
  __syncthreads();

  for (int t = t0; t < t1; ++t) {
    // ---- stage h slice (16 x 1024 f16 = 32KB) into fragment-order LDS ----
    // thread loads b = 2p+srow0 (p=0..7), k-octet ccol -> coalesced 16B loads
    {
      const _Float16* gb = h16 + (size_t)(t & 1) * 65536 + ((size_t)bg << 14)
                           + (srow0 << 10) + (ccol << 3);
      f32x4 r0, r1, r2, r3, r4, r5, r6, r7;
      asm volatile(
        "global_load_dwordx4 %0, %8, off sc0 sc1\n\t"
        "global_load_dwordx4 %1, %9, off sc0 sc1\n\t"
        "global_load_dwordx4 %2, %10, off sc0 sc1\n\t"
        "global_load_dwordx4 %3, %11, off sc0 sc1\n\t"
        "global_load_dwordx4 %4, %12, off sc0 sc1\n\t"
        "global_load_dwordx4 %5, %13, off sc0 sc1\n\t"
        "global_load_dwordx4 %6, %14, off sc0 sc1\n\t"
        "global_load_dwordx4 %7, %15, off sc0 sc1\n\t"
        "s_waitcnt vmcnt(0)"
        : "=&v"(r0), "=&v"(r1), "=&v"(r2), "=&v"(r3),
          "=&v"(r4), "=&v"(r5), "=&v"(r6), "=&v"(r7)
        : "v"(gb), "v"(gb + 2048), "v"(gb + 4096), "v"(gb + 6144),
          "v"(gb + 8192), "v"(gb + 10240), "v"(gb + 12288), "v"(gb + 14336)
        : "memory");
      _Float16* lb0 = &hs[ccol << 7];
      *(f32x4*)(lb0 + (((srow0     ) ^ cx) << 3)) = r0;
      *(f32x4*)(lb0 + (((srow0 +  2) ^ cx) << 3)) = r1;
      *(f32x4*)(lb0 + (((srow0 +  4) ^ cx) << 3)) = r2;
      *(f32x4*)(lb0 + (((srow0 +  6) ^ cx) << 3)) = r3;
      *(f32x4*)(lb0 + (((srow0 +  8) ^ cx) << 3)) = r4;
      *(f32x4*)(lb0 + (((srow0 + 10) ^ cx) << 3)) = r5;
      *(f32x4*)(lb0 + (((srow0 + 12) ^ cx) << 3)) = r6;
      *(f32x4*)(lb0 + (((srow0 + 14) ^ cx) << 3)) = r7;
    }
    __syncthreads();

    // ---- matvec: wave w x its k-slice, 4 row-tiles, 4 indep acc chains ----
    half8 af[8];
#pragma unroll
    for (int kt = 0; kt < 8; ++kt) {
      int c = c0 + (kt << 2);
      af[kt] = *(const half8*)&hs[(c << 7) + (((lane & 15) ^ (c & 15)) << 3)];
    }
    f32x4 a0 = {0.f,0.f,0.f,0.f}, a1 = a0, a2 = a0, a3 = a0;
#pragma unroll
    for (int kt = 0; kt < 8; ++kt) {
      a0 = __builtin_amdgcn_mfma_f32_16x16x32_f16(af[kt], Bf[0][kt], a0, 0, 0, 0);
      a1 = __builtin_amdgcn_mfma_f32_16x16x32_f16(af[kt], Bf[1][kt], a1, 0, 0, 0);
      a2 = __builtin_amdgcn_mfma_f32_16x16x32_f16(af[kt], Bf[2][kt], a2, 0, 0, 0);
      a3 = __builtin_amdgcn_mfma_f32_16x16x32_f16(af[kt], Bf[3][kt], a3, 0, 0, 0);
    }
    // C layout: col = lane&15 (local U row within tile), row = (lane>>4)*4+r (batch)
    {
      int l = lane & 15, q = lane >> 4;
      *(f32x4*)&part[(w * 1280) + (l      ) * 20 + (q << 2)] = a0;
      *(f32x4*)&part[(w * 1280) + (l + 16) * 20 + (q << 2)] = a1;
      *(f32x4*)&part[(w * 1280) + (l + 32) * 20 + (q << 2)] = a2;
      *(f32x4*)&part[(w * 1280) + (l + 48) * 20 + (q << 2)] = a3;
    }
    __syncthreads();

    // ---- cross-wave reduce + pointwise GRU (thread owns (lb, jl)) ----
    float g0 = 0.f, g1 = 0.f, g2 = 0.f, g3 = 0.f;
    int rowb = jl << 2;
#pragma unroll
    for (int ww = 0; ww < 4; ++ww) {
      const float* pb = &part[ww * 1280 + rowb * 20 + lb];
      g0 += pb[0]; g1 += pb[20]; g2 += pb[40]; g3 += pb[60];
    }
    int tok = ltok[(lb << 9) + t];
    const float* te = tebase + tok * 3072;
    float te0 = te[0], te1 = te[1024], te2 = te[2048];
    float rr = 1.f / (1.f + __expf(-(g0 + te0)));
    float zz = 1.f / (1.f + __expf(-(g1 + te1)));
    float xx = g2 + te2 + rr * (g3 + bhhn);
    float e2 = __expf(2.f * xx);
    float nv = 1.f - 2.f / (e2 + 1.f);      // tanh(xx), saturates cleanly
    float hnew = (1.f - zz) * nv + zz * hold;
    hold = hnew;
    hrep[lb * 24 + jl] = (_Float16)hnew;
    __syncthreads();

    // ---- writeback: wave0 -> h16 coherent; wave1 -> tops (off critical path) ----
    if (tid < 32) {
      int wb = tid >> 1, cc = tid & 1;
      f32x4 v = *(const f32x4*)&hrep[wb * 24 + (cc << 3)];
      _Float16* dst = h16 + (size_t)((t + 1) & 1) * 65536
                      + ((size_t)((bg << 4) + wb) << 10) + (rg << 4) + (cc << 3);
      asm volatile("global_store_dwordx4 %0, %1, off sc0 sc1" :: "v"(dst), "v"(v) : "memory");
    }
    asm volatile("s_waitcnt vmcnt(0)" ::: "memory");
    if (tid >= 64 && tid < 96) {
      int wb = (tid - 64) >> 1, cc = tid & 1;
      f32x4 v = *(const f32x4*)&hrep[wb * 24 + (cc << 3)];
      *(f32x4*)(tops + ((size_t)(t - t0) << 16)
                + ((size_t)((bg << 4) + wb) << 10) + (rg << 4) + (cc << 3)) = v;
    }

    // ---- inline grid barrier: 8 split counters, 64B apart, slot = step t ----
    if (tid < 8) {
      unsigned int* line = bar + (t << 7) + (tid << 4);
      if (tid == (int)(blockIdx.x & 7))
        __hip_atomic_fetch_add(line, 1u, __ATOMIC_RELAXED, __HIP_MEMORY_SCOPE_AGENT);
      while (__hip_atomic_load(line, __ATOMIC_RELAXED, __HIP_MEMORY_SCOPE_AGENT) != 32u) {}
    }
    __syncthreads();
  }
  h32[(b << 10) + j] = hold;
}

// ============================================================================
extern "C" void kernel_launch(void* const* d_in, const int* in_sizes, int n_in,
                              void* d_out, int out_size, void* d_ws, size_t ws_size,
                              hipStream_t stream) {
  const int*   tokens = (const int*)d_in[0];
  const float* embed  = (const float*)d_in[1];
  const float* W_ih   = (const float*)d_in[2];
  const float* W_hh   = (const float*)d_in[3];
  const float* b_ih   = (const float*)d_in[4];
  const float* b_hh   = (const float*)d_in[5];
  const float* h0     = (const float*)d_in[6];
  const float* dec_W1 = (const float*)d_in[7];
  const float* dec_b1 = (const float*)d_in[8];
  const float* dec_W2 = (const float*)d_in[9];
  const float* dec_b2 = (const float*)d_in[10];
  float* out = (float*)d_out;
  (void)in_sizes; (void)n_in; (void)out_size;

  char* ws = (char*)d_ws;
  size_t off = 0;
  auto alloc = [&](size_t bytes) -> char* {
    char* p = ws + off;
    off = (off + bytes + 255) & ~(size_t)255;
    return p;
  };
  _Float16* U16     = (_Float16*)alloc((size_t)4096 * 1024 * 2);
  float*    Te      = (float*)alloc((size_t)256 * 3072 * 4);
  float*    te_bias = (float*)alloc(3072 * 4);
  _Float16* embed16 = (_Float16*)alloc(131072 * 2);
  _Float16* wihe16  = (_Float16*)alloc((size_t)1572864 * 2);
  _Float16* w1t16   = (_Float16*)alloc(524288 * 2);
  _Float16* w2t16   = (_Float16*)alloc(131072 * 2);
  float*    h32     = (float*)alloc(65536 * 4);
  _Float16* h16     = (_Float16*)alloc((size_t)2 * 65536 * 2);
  unsigned int* bar = (unsigned int*)alloc((size_t)65536 * 4);
  size_t fixed = off;

  size_t per_t = (size_t)(65536 + 32768) * 2;
  long remain = (long)ws_size - (long)fixed - 1024;
  int chunk_T = remain > 0 ? (int)(remain / (long)per_t) : 0;
  chunk_T &= ~1;
  if (chunk_T > 512) chunk_T = 512;
  if (chunk_T < 2) chunk_T = 2;
  _Float16* tops = (_Float16*)alloc((size_t)chunk_T * 65536 * 2);
  _Float16* hdec = (_Float16*)alloc((size_t)chunk_T * 32768 * 2);

  prep_misc_kernel<<<9740, 256, 0, stream>>>(embed, W_ih, dec_W1, dec_W2, b_ih, b_hh, h0,
                                             embed16, wihe16, w1t16, w2t16, te_bias, h32, h16, bar);
  prep_u_kernel<<<16384, 256, 0, stream>>>(W_ih, W_hh, U16);
  gemm_bt_kernel<<<2 * 24, 256, 0, stream>>>(embed16, wihe16, te_bias, Te, nullptr,
                                             256, 3072, 512, 0, 0);

  for (int t0 = 0; t0 < 512; t0 += chunk_T) {
    int t1 = t0 + chunk_T; if (t1 > 512) t1 = 512;
    void* args[] = {&U16, &Te, (void*)&tokens, (void*)&b_hh, &h32, &h16, &tops, &bar, &t0, &t1};
    hipLaunchCooperativeKernel((const void*)recur_kernel, dim3(256), dim3(256), args, 0, stream);
    int Mc = (t1 - t0) * 64;
    gemm_bt_kernel<<<(Mc / 128) * 4, 256, 0, stream>>>(tops, w1t16, dec_b1, nullptr, hdec,
                                                       Mc, 512, 1024, 1, 0);
    gemm_bt_kernel<<<(Mc / 128) * 2, 256, 0, stream>>>(hdec, w2t16, dec_b2, out, nullptr,
                                                       Mc, 256, 512, 2, t0);
  }
}